// Round 24
// baseline (39.401 us; speedup 1.0000x reference)
//
#include <hip/hip_runtime.h>

#define B_ 64
#define S_ 512
#define H_ 768
#define L_ 9
#define EMP 16                  // padded emission row stride in global (floats)
#define CH 16                   // timesteps per chunk
#define NCHUNK 32               // chunks per batch
#define CPAD 88                 // floats per chunk record in LDS (16B-aligned)

typedef __attribute__((ext_vector_type(8))) short bf16x8;
typedef __attribute__((ext_vector_type(4))) float f32x4;
typedef bf16x8 __attribute__((may_alias)) bf16x8_a;
typedef uint2  __attribute__((may_alias)) uint2_a;

// eem LDS offset for timestep t: 16B-aligned, bank-staggered per 16-row group
__device__ __forceinline__ int eoff(int t) { return t * 12 + (t >> 4) * 4; }

// pack two fp32 -> one u32 of two bf16 (round-to-nearest via +0x8000)
__device__ __forceinline__ unsigned pack_bf16(float lo, float hi) {
    unsigned a = __float_as_uint(lo) + 0x8000u;
    unsigned b = __float_as_uint(hi) + 0x8000u;
    return __builtin_amdgcn_perm(b, a, 0x07060302);  // {b.b23, a.b23}
}

// ---------------------------------------------------------------------------
// Kernel A (MFMA, coalesced-staged, WORK-STEALING): partial em = hidden@W+b.
// 256 blocks x 512 threads (8 waves), one block per CU. Work item = 16-row
// tile x K-half (4096 items, 24 KB each). 8 groups of 512 items; group q =
// blockIdx&7 has its own counter (64B apart). Each wave: one STATIC first
// item (sblk*8+wv, burst-free), then STEALS 256+atomicAdd until group empty.
// Greedy schedule -> makespan ~ optimal + 1 item (r23's static mapping left a
// stochastic +3sigma ~ 2x-mean worst-CU tail that no static map can fix).
// Per-item: r23's coalesced global->reg->bf16->LDS panel pipeline, 6 panels.
// kh=0 items add bias and write em0; kh=1 write em1; CRF sums them (r12).
// Also zeroes out[0] (runs before the CRF kernel in stream order).
// ---------------------------------------------------------------------------
__global__ __launch_bounds__(512) void emis_kernel(
    const float* __restrict__ hidden, const float* __restrict__ W,
    const float* __restrict__ bias, const int* __restrict__ lengths,
    float* __restrict__ em0, float* __restrict__ em1,
    int* __restrict__ ctr, float* __restrict__ out)
{
    __shared__ unsigned Wl[96 * 16 * 4];     // bf16x8 frags [k8][col] (24 KB)
    __shared__ float bias16[16];
    __shared__ unsigned hbuf[8][2][16 * 36]; // per-wave panels: 16 rows x 144B

    const int T = threadIdx.x;
    if (blockIdx.x == 0 && T == 0) out[0] = 0.0f;

    const int g = blockIdx.x;                // 0..255
    const int grp = g & 7;                   // item group
    const int sblk = g >> 3;                 // 0..31 within group

    const int wv = T >> 6, lane = T & 63;
    const int q = lane >> 4, col = lane & 15;
    const int srow = lane >> 2, sm = lane & 3;

    // ---- pack W fragments from global W (L1/L2-resident) ----
    if (T < 16) bias16[T] = (T < 9) ? bias[T] : 0.0f;
    #pragma unroll
    for (int r3 = 0; r3 < 3; ++r3) {
        const int sidx = T + 512 * r3;       // 0..1535
        const int k8 = sidx >> 4, c = sidx & 15;
        unsigned w0 = 0, w1 = 0, w2 = 0, w3 = 0;
        if (c < 9) {
            const float* wp = W + (size_t)(k8 * 8) * 9 + c;
            w0 = pack_bf16(wp[0],  wp[9]);
            w1 = pack_bf16(wp[18], wp[27]);
            w2 = pack_bf16(wp[36], wp[45]);
            w3 = pack_bf16(wp[54], wp[63]);
        }
        uint4 v = { w0, w1, w2, w3 };
        *(uint4*)&Wl[sidx * 4] = v;
    }
    __syncthreads();

    unsigned* buf0 = &hbuf[wv][0][0];
    unsigned* buf1 = &hbuf[wv][1][0];
    const int woff = srow * 36 + sm * 2;     // u32 write offset (+ m*8)
    const int rdoff = col * 36 + q * 4;      // u32 read offset (+ s*16)
    const float4 bias4 = *(const float4*)(bias16 + q * 4);
    int* myctr = ctr + grp * 16;             // 64B-spaced counters

    int item = sblk * 8 + wv;                // static first item, 0..255

    #pragma unroll 1
    for (;;) {
        const int gitem = (grp << 9) + item; // 0..4095
        const int kh   = gitem & 1;          // K-half
        const int tile = gitem >> 1;         // 0..2047
        const int b    = tile >> 5;
        const int s0   = (tile & 31) << 4;
        int len = lengths[b]; if (len < 1) len = 1;

        if (s0 < len) {
            const float* hrow = hidden
                + (size_t)((b << 9) + s0 + srow) * H_ + kh * 384 + sm * 4;

            // prefetch panels 0,1
            float4 L[2][4];
            #pragma unroll
            for (int m = 0; m < 4; ++m) L[0][m] = *(const float4*)(hrow + m * 16);
            #pragma unroll
            for (int m = 0; m < 4; ++m) L[1][m] = *(const float4*)(hrow + 64 + m * 16);

            // write panel 0
            #pragma unroll
            for (int m = 0; m < 4; ++m) {
                uint2 u = { pack_bf16(L[0][m].x, L[0][m].y),
                            pack_bf16(L[0][m].z, L[0][m].w) };
                *(uint2_a*)(buf0 + woff + m * 8) = u;
            }

            f32x4 acc = { 0.0f, 0.0f, 0.0f, 0.0f };
            #pragma unroll
            for (int p = 0; p < 6; ++p) {
                unsigned* cbuf = (p & 1) ? buf1 : buf0;
                unsigned* nbuf = (p & 1) ? buf0 : buf1;

                if (p + 2 < 6) {
                    #pragma unroll
                    for (int m = 0; m < 4; ++m)
                        L[p & 1][m] = *(const float4*)(hrow + (p + 2) * 64 + m * 16);
                }
                #pragma unroll
                for (int s = 0; s < 2; ++s) {
                    const bf16x8 bu = *(const bf16x8_a*)(cbuf + rdoff + s * 16);
                    const int k8 = kh * 48 + (p * 2 + s) * 4 + q;
                    const uint4 a4 = *(const uint4*)&Wl[(k8 * 16 + col) * 4];
                    union { unsigned u[4]; bf16x8 v; } au;
                    au.u[0] = a4.x; au.u[1] = a4.y; au.u[2] = a4.z; au.u[3] = a4.w;
                    acc = __builtin_amdgcn_mfma_f32_16x16x32_bf16(au.v, bu, acc, 0, 0, 0);
                }
                if (p + 1 < 6) {
                    #pragma unroll
                    for (int m = 0; m < 4; ++m) {
                        uint2 u = { pack_bf16(L[(p + 1) & 1][m].x, L[(p + 1) & 1][m].y),
                                    pack_bf16(L[(p + 1) & 1][m].z, L[(p + 1) & 1][m].w) };
                        *(uint2_a*)(nbuf + woff + m * 8) = u;
                    }
                }
            }

            const int srow_out = s0 + col;
            if (srow_out < len) {
                float4 o;
                if (kh == 0) {
                    o.x = acc[0] + bias4.x; o.y = acc[1] + bias4.y;
                    o.z = acc[2] + bias4.z; o.w = acc[3] + bias4.w;
                } else {
                    o.x = acc[0]; o.y = acc[1]; o.z = acc[2]; o.w = acc[3];
                }
                float* dst = (kh ? em1 : em0)
                           + (size_t)((b << 9) + srow_out) * EMP + q * 4;
                *(float4*)dst = o;
            }
        }

        // steal next item (counter zeroed per launch by memset)
        int r;
        if (lane == 0) r = atomicAdd(myctr, 1);
        r = __shfl(r, 0, 64);
        if (r >= 256) break;
        item = 256 + r;
    }
}

// ---------------------------------------------------------------------------
// Kernel B (fused CRF): one block per batch, 384 threads.  (r12 version:
// emissions read as em0 + em1 partial sums.)
//  phase 0: Pl=exp(trans) -> LDS; eem=exp(em0+em1) -> LDS for t<len only.
//  phase 1: T<288: build 32 chunk transfer matrices (1 chunk/thread, row i);
//           T>=320: gold-path numerator.
//  phase 2: binary tree product of the 32 matrices (5 levels, adaptive
//           rescale, logs in LDS), then thread 0 applies alpha0 and end_t.
// ---------------------------------------------------------------------------
__global__ __launch_bounds__(384, 1) void crf_kernel(
    const float* __restrict__ em0, const float* __restrict__ em1,
    const int* __restrict__ labels, const int* __restrict__ lengths,
    const float* __restrict__ start_t, const float* __restrict__ trans,
    const float* __restrict__ end_t, float* __restrict__ out)
{
    __shared__ float eem[6288];              // staggered exp(em) rows, 24.6 KiB
    __shared__ float Pl[112];                // exp(trans), rows padded to 12
    __shared__ float Cs[NCHUNK * CPAD];      // chunk matrices, 11 KiB
    __shared__ float Cs2[16 * CPAD];         // tree ping-pong, 5.5 KiB
    __shared__ float rmx_s[16 * 12];
    __shared__ float lgA[32], lgB[16];
    const int T = threadIdx.x;
    const int b = blockIdx.x;
    int len = lengths[b]; if (len < 1) len = 1;

    // ---- phase 0: shared tables ----
    if (T < 81) {
        const int k = T / 9, j = T - 9 * k;
        Pl[k * 12 + j] = __expf(trans[T]);
    }
    #pragma unroll
    for (int r = 0; r < 2; ++r) {
        const int t = T + 384 * r;
        if (t < len) {                       // rows >= len are never used
            const int o = eoff(t);
            const size_t off = (size_t)((b << 9) + t) * EMP;
            const float4* p0 = (const float4*)(em0 + off);
            const float4* p1 = (const float4*)(em1 + off);
            float4 a0 = p0[0], a1 = p0[1], a2 = p0[2];
            float4 b0 = p1[0], b1 = p1[1], b2 = p1[2];
            float4 w0 = { __expf(a0.x + b0.x), __expf(a0.y + b0.y),
                          __expf(a0.z + b0.z), __expf(a0.w + b0.w) };
            float4 w1 = { __expf(a1.x + b1.x), __expf(a1.y + b1.y),
                          __expf(a1.z + b1.z), __expf(a1.w + b1.w) };
            *(float4*)(eem + o) = w0;
            *(float4*)(eem + o + 4) = w1;
            eem[o + 8] = __expf(a2.x + b2.x);
        }
    }
    if (T < 32) lgA[T] = 0.0f;
    __syncthreads();

    // ---- phase 1 ----
    if (T < 288) {
        const int c = T / 9;                 // 0..31, one chunk per thread
        const int i = T - 9 * c;
        float A[9];
        #pragma unroll
        for (int j = 0; j < 9; ++j) A[j] = (i == j) ? 1.0f : 0.0f;
        const int t0 = CH * c + 1;

        #pragma unroll 1
        for (int s = 0; s < CH; ++s) {
            const int t = t0 + s;
            const int o = eoff(t);
            float4 e0 = *(const float4*)(eem + o);
            float4 e1 = *(const float4*)(eem + o + 4);
            const float e8 = eem[o + 8];
            const float e[9] = { e0.x, e0.y, e0.z, e0.w,
                                 e1.x, e1.y, e1.z, e1.w, e8 };

            float an[9];
            #pragma unroll
            for (int j = 0; j < 9; ++j) an[j] = 0.0f;
            #pragma unroll
            for (int k = 0; k < 9; ++k) {
                float4 p0 = *(const float4*)(Pl + k * 12);
                float4 p1 = *(const float4*)(Pl + k * 12 + 4);
                const float p8 = Pl[k * 12 + 8];
                const float pr[9] = { p0.x, p0.y, p0.z, p0.w,
                                      p1.x, p1.y, p1.z, p1.w, p8 };
                const float ak = A[k];
                #pragma unroll
                for (int j = 0; j < 9; ++j)
                    an[j] = fmaf(ak, pr[j], an[j]);
            }
            const bool live = (t < len);
            #pragma unroll
            for (int j = 0; j < 9; ++j)
                A[j] = live ? an[j] * e[j] : A[j];
            if (s == 7) {                    // exact 2^-40; constant added at end
                #pragma unroll
                for (int j = 0; j < 9; ++j) A[j] *= 0x1p-40f;
            }
        }
        #pragma unroll
        for (int j = 0; j < 9; ++j) Cs[c * CPAD + i * 9 + j] = A[j];
    } else if (T >= 320) {
        // ---- numerator ----
        const int lane = T - 320;
        const int* lab = labels + (size_t)b * S_;
        float part = 0.0f;
        for (int t = 1 + lane; t < len; t += 64) {
            const int tp = lab[t - 1], tc = lab[t];
            const size_t idx = (size_t)((b << 9) + t) * EMP + tc;
            part += trans[tp * 9 + tc] + em0[idx] + em1[idx];
        }
        #pragma unroll
        for (int off = 32; off >= 1; off >>= 1) part += __shfl_xor(part, off, 64);
        if (lane == 0) {
            const int l0 = lab[0], le = lab[len - 1];
            const size_t i0 = (size_t)(b << 9) * EMP + l0;
            const float num = start_t[l0] + em0[i0] + em1[i0]
                            + part + end_t[le];
            atomicAdd(out, -num);
        }
    }
    __syncthreads();

    // ---- phase 2a: binary tree product of 32 chunk matrices (5 levels) ----
    float* src = Cs;  float* dst = Cs2;
    float* ls  = lgA; float* ld  = lgB;
    int nn = 16;                             // output nodes this level
    #pragma unroll 1
    for (int lvl = 0; lvl < 5; ++lvl) {
        const int n = T / 9, i = T - 9 * n;
        float row[9];
        if (T < nn * 9) {
            const float* Am = src + (2 * n) * CPAD;
            const float* Bm = src + (2 * n + 1) * CPAD;
            float a[9];
            #pragma unroll
            for (int k = 0; k < 9; ++k) a[k] = Am[i * 9 + k];
            #pragma unroll
            for (int j = 0; j < 9; ++j) row[j] = 0.0f;
            #pragma unroll
            for (int k = 0; k < 9; ++k) {
                const float ak = a[k];
                #pragma unroll
                for (int j = 0; j < 9; ++j)
                    row[j] = fmaf(ak, Bm[k * 9 + j], row[j]);
            }
            float rmx = row[0];
            #pragma unroll
            for (int j = 1; j < 9; ++j) rmx = fmaxf(rmx, row[j]);
            rmx_s[n * 12 + i] = rmx;
        }
        __syncthreads();
        if (T < nn * 9) {
            float mx = rmx_s[n * 12];
            #pragma unroll
            for (int k = 1; k < 9; ++k) mx = fmaxf(mx, rmx_s[n * 12 + k]);
            const float inv = 1.0f / mx;
            #pragma unroll
            for (int j = 0; j < 9; ++j) dst[n * CPAD + i * 9 + j] = row[j] * inv;
            if (i == 0) ld[n] = ls[2 * n] + ls[2 * n + 1] + __logf(mx);
        }
        __syncthreads();
        float* t1 = src; src = dst; dst = t1;
        float* t2 = ls;  ls = ld;  ld = t2;
        nn >>= 1;
    }
    // src = final normalized matrix (node 0), ls[0] = accumulated log

    // ---- phase 2b: apply alpha0 and end transitions ----
    if (T == 0) {
        const size_t off0 = (size_t)(b << 9) * EMP;
        const float4* p0 = (const float4*)(em0 + off0);
        const float4* p1 = (const float4*)(em1 + off0);
        float4 a0 = p0[0], a1 = p0[1], a2 = p0[2];
        float4 b0 = p1[0], b1 = p1[1], b2 = p1[2];
        float al[9] = { a0.x + b0.x + start_t[0], a0.y + b0.y + start_t[1],
                        a0.z + b0.z + start_t[2], a0.w + b0.w + start_t[3],
                        a1.x + b1.x + start_t[4], a1.y + b1.y + start_t[5],
                        a1.z + b1.z + start_t[6], a1.w + b1.w + start_t[7],
                        a2.x + b2.x + start_t[8] };
        float m0 = al[0];
        #pragma unroll
        for (int j = 1; j < 9; ++j) m0 = fmaxf(m0, al[j]);
        float alpha[9];
        #pragma unroll
        for (int j = 0; j < 9; ++j) alpha[j] = __expf(al[j] - m0);

        float ev = 0.0f;
        #pragma unroll
        for (int j = 0; j < 9; ++j) {
            float s = 0.0f;
            #pragma unroll
            for (int i = 0; i < 9; ++i)
                s = fmaf(alpha[i], src[i * 9 + j], s);
            ev = fmaf(s, __expf(end_t[j]), ev);
        }
        // 32 chunks x 2^-40 scaling -> +1280*ln2 exact constant
        const float den = m0 + ls[0] + __logf(ev)
                        + 1280.0f * 0.6931471805599453f;
        atomicAdd(out, den);
    }
}

// ---------------------------------------------------------------------------
extern "C" void kernel_launch(void* const* d_in, const int* in_sizes, int n_in,
                              void* d_out, int out_size, void* d_ws, size_t ws_size,
                              hipStream_t stream)
{
    (void)in_sizes; (void)n_in; (void)out_size; (void)ws_size;
    const float* hidden  = (const float*)d_in[0];
    const float* W       = (const float*)d_in[1];
    const float* bias    = (const float*)d_in[2];
    const float* start_t = (const float*)d_in[3];
    const float* trans   = (const float*)d_in[4];
    const float* end_t   = (const float*)d_in[5];
    const int*   labels  = (const int*)d_in[6];
    const int*   lengths = (const int*)d_in[7];

    float* em0 = (float*)d_ws;                          // 64*512*16 floats
    float* em1 = em0 + (size_t)B_ * S_ * EMP;           // 64*512*16 floats
    int*   ctr = (int*)(em1 + (size_t)B_ * S_ * EMP);   // 8 counters, 64B apart
    float* out = (float*)d_out;

    hipMemsetAsync(ctr, 0, 8 * 16 * sizeof(int), stream);
    emis_kernel<<<256, 512, 0, stream>>>(hidden, W, bias, lengths,
                                         em0, em1, ctr, out);
    crf_kernel<<<B_, 384, 0, stream>>>(em0, em1, labels, lengths,
                                       start_t, trans, end_t, out);
}

// Round 25
// 27.923 us; speedup vs baseline: 1.4110x; 1.4110x over previous
//
#include <hip/hip_runtime.h>

#define B_ 64
#define S_ 512
#define H_ 768
#define L_ 9
#define EMP 16                  // padded emission row stride in global (floats)
#define CH 16                   // timesteps per chunk
#define NCHUNK 32               // chunks per batch
#define CPAD 88                 // floats per chunk record in LDS (16B-aligned)

typedef __attribute__((ext_vector_type(8))) short bf16x8;
typedef __attribute__((ext_vector_type(4))) float f32x4;
typedef bf16x8 __attribute__((may_alias)) bf16x8_a;
typedef uint2  __attribute__((may_alias)) uint2_a;

// eem LDS offset for timestep t: 16B-aligned, bank-staggered per 16-row group
__device__ __forceinline__ int eoff(int t) { return t * 12 + (t >> 4) * 4; }

// pack two fp32 -> one u32 of two bf16 (round-to-nearest via +0x8000)
__device__ __forceinline__ unsigned pack_bf16(float lo, float hi) {
    unsigned a = __float_as_uint(lo) + 0x8000u;
    unsigned b = __float_as_uint(hi) + 0x8000u;
    return __builtin_amdgcn_perm(b, a, 0x07060302);  // {b.b23, a.b23}
}

// ---------------------------------------------------------------------------
// Kernel A (MFMA, coalesced-staged, mean-exact balanced): em = hidden@W+b.
// 256 blocks x 512 threads (8 waves), one block per CU. Wave w of block g:
//   pos   = 4w + ((g>>6) ^ (w&3))      (position multiset sum = 124 for ALL
//                                       blocks -> E[live]=4.125 everywhere)
//   batch = (g + 9w) & 63              (8 spread batches, decorrelated sets)
// Bijective over all 2048 tiles: w=pos>>2, g>>6=(pos&3)^(w&3), g&63=(b-9w)%64.
// Hidden stream: coalesced global->reg->bf16 pack->per-wave LDS panel
// (double-buffered, 144B rows)->ds_read_b128 fragments; no K-loop barriers.
// Also zeroes out[0] (runs before the CRF kernel in stream order).
// [r24 post-mortem: dynamic work-stealing regressed 11.5us (steal-atomic
//  latency at item boundaries + dead-item steals) -> static mapping is final.]
// ---------------------------------------------------------------------------
__global__ __launch_bounds__(512) void emis_kernel(
    const float* __restrict__ hidden, const float* __restrict__ W,
    const float* __restrict__ bias, const int* __restrict__ lengths,
    float* __restrict__ em, float* __restrict__ out)
{
    __shared__ unsigned Wl[96 * 16 * 4];     // bf16x8 frags [k8][col] (24 KB)
    __shared__ float bias16[16];
    __shared__ unsigned hbuf[8][2][16 * 36]; // per-wave panels: 16 rows x 144B

    const int T = threadIdx.x;
    if (blockIdx.x == 0 && T == 0) out[0] = 0.0f;

    const int g = blockIdx.x;                // 0..255

    const int wv = T >> 6, lane = T & 63;
    const int q = lane >> 4, col = lane & 15;

    const int b   = (g + 9 * wv) & 63;               // batch 0..63
    const int pos = 4 * wv + ((g >> 6) ^ (wv & 3));  // 0..31
    const int s0  = pos * 16;                // row-in-batch base
    int len = lengths[b]; if (len < 1) len = 1;
    const bool tile_live = (s0 < len);
    const int row_abs = (b << 9) + s0;       // absolute row base

    // stager mapping: lane -> (row l>>2, 16B at (l&3)*16 of each 64B run)
    const int srow = lane >> 2, sm = lane & 3;
    const float* hrow = hidden + (size_t)(row_abs + srow) * H_ + sm * 4;

    // ---- prefetch panels 0,1 (coalesced; starts HBM stream pre-barrier) ----
    float4 L[2][4];
    if (tile_live) {
        #pragma unroll
        for (int m = 0; m < 4; ++m) L[0][m] = *(const float4*)(hrow + m * 16);
        #pragma unroll
        for (int m = 0; m < 4; ++m) L[1][m] = *(const float4*)(hrow + 64 + m * 16);
    }

    // ---- pack W fragments from global W (L1/L2-resident) ----
    if (T < 16) bias16[T] = (T < 9) ? bias[T] : 0.0f;
    #pragma unroll
    for (int r3 = 0; r3 < 3; ++r3) {
        const int sidx = T + 512 * r3;       // 0..1535
        const int k8 = sidx >> 4, c = sidx & 15;
        unsigned w0 = 0, w1 = 0, w2 = 0, w3 = 0;
        if (c < 9) {
            const float* wp = W + (size_t)(k8 * 8) * 9 + c;
            w0 = pack_bf16(wp[0],  wp[9]);
            w1 = pack_bf16(wp[18], wp[27]);
            w2 = pack_bf16(wp[36], wp[45]);
            w3 = pack_bf16(wp[54], wp[63]);
        }
        uint4 v = { w0, w1, w2, w3 };
        *(uint4*)&Wl[sidx * 4] = v;
    }
    __syncthreads();

    if (!tile_live) return;

    unsigned* buf0 = &hbuf[wv][0][0];
    unsigned* buf1 = &hbuf[wv][1][0];
    const int woff = srow * 36 + sm * 2;     // u32 write offset (+ m*8)
    const int rdoff = col * 36 + q * 4;      // u32 read offset (+ s*16)

    // write panel 0
    #pragma unroll
    for (int m = 0; m < 4; ++m) {
        uint2 u = { pack_bf16(L[0][m].x, L[0][m].y),
                    pack_bf16(L[0][m].z, L[0][m].w) };
        *(uint2_a*)(buf0 + woff + m * 8) = u;
    }

    const float4 bias4 = *(const float4*)(bias16 + q * 4);
    f32x4 acc = { 0.0f, 0.0f, 0.0f, 0.0f };

    #pragma unroll
    for (int p = 0; p < 12; ++p) {
        unsigned* cbuf = (p & 1) ? buf1 : buf0;
        unsigned* nbuf = (p & 1) ? buf0 : buf1;

        // prefetch panel p+2 into L[p&1] (its panel p already in LDS)
        if (p + 2 < 12) {
            #pragma unroll
            for (int m = 0; m < 4; ++m)
                L[p & 1][m] = *(const float4*)(hrow + (p + 2) * 64 + m * 16);
        }

        // consume panel p: 2 MFMA steps
        #pragma unroll
        for (int s = 0; s < 2; ++s) {
            const bf16x8 bu = *(const bf16x8_a*)(cbuf + rdoff + s * 16);
            const uint4 a4 =
                *(const uint4*)&Wl[(((p * 2 + s) * 4 + q) * 16 + col) * 4];
            union { unsigned u[4]; bf16x8 v; } au;
            au.u[0] = a4.x; au.u[1] = a4.y; au.u[2] = a4.z; au.u[3] = a4.w;
            acc = __builtin_amdgcn_mfma_f32_16x16x32_bf16(au.v, bu, acc, 0, 0, 0);
        }

        // write panel p+1
        if (p + 1 < 12) {
            #pragma unroll
            for (int m = 0; m < 4; ++m) {
                uint2 u = { pack_bf16(L[(p + 1) & 1][m].x, L[(p + 1) & 1][m].y),
                            pack_bf16(L[(p + 1) & 1][m].z, L[(p + 1) & 1][m].w) };
                *(uint2_a*)(nbuf + woff + m * 8) = u;
            }
        }
    }

    const int srow_out = s0 + col;
    if (srow_out < len) {
        float4 o = { acc[0] + bias4.x, acc[1] + bias4.y,
                     acc[2] + bias4.z, acc[3] + bias4.w };
        *(float4*)(em + (size_t)((b << 9) + srow_out) * EMP + q * 4) = o;
    }
}

// ---------------------------------------------------------------------------
// Kernel B (fused CRF): one block per batch, 384 threads.
//  phase 0: Pl=exp(trans) -> LDS; eem=exp(em) -> LDS for t<len only.
//  phase 1: T<288: build 32 chunk transfer matrices (1 chunk/thread, row i);
//           T>=320: gold-path numerator.
//  phase 2: binary tree product of the 32 matrices (5 levels, adaptive
//           rescale, logs in LDS), then thread 0 applies alpha0 and end_t.
// ---------------------------------------------------------------------------
__global__ __launch_bounds__(384, 1) void crf_kernel(
    const float* __restrict__ em, const int* __restrict__ labels,
    const int* __restrict__ lengths, const float* __restrict__ start_t,
    const float* __restrict__ trans, const float* __restrict__ end_t,
    float* __restrict__ out)
{
    __shared__ float eem[6288];              // staggered exp(em) rows, 24.6 KiB
    __shared__ float Pl[112];                // exp(trans), rows padded to 12
    __shared__ float Cs[NCHUNK * CPAD];      // chunk matrices, 11 KiB
    __shared__ float Cs2[16 * CPAD];         // tree ping-pong, 5.5 KiB
    __shared__ float rmx_s[16 * 12];
    __shared__ float lgA[32], lgB[16];
    const int T = threadIdx.x;
    const int b = blockIdx.x;
    int len = lengths[b]; if (len < 1) len = 1;

    // ---- phase 0: shared tables ----
    if (T < 81) {
        const int k = T / 9, j = T - 9 * k;
        Pl[k * 12 + j] = __expf(trans[T]);
    }
    #pragma unroll
    for (int r = 0; r < 2; ++r) {
        const int t = T + 384 * r;
        if (t < len) {                       // rows >= len are never used
            const int o = eoff(t);
            const float4* p = (const float4*)(em + (size_t)((b << 9) + t) * EMP);
            float4 v0 = p[0], v1 = p[1], v2 = p[2];
            float4 w0 = { __expf(v0.x), __expf(v0.y), __expf(v0.z), __expf(v0.w) };
            float4 w1 = { __expf(v1.x), __expf(v1.y), __expf(v1.z), __expf(v1.w) };
            *(float4*)(eem + o) = w0;
            *(float4*)(eem + o + 4) = w1;
            eem[o + 8] = __expf(v2.x);
        }
    }
    if (T < 32) lgA[T] = 0.0f;
    __syncthreads();

    // ---- phase 1 ----
    if (T < 288) {
        const int c = T / 9;                 // 0..31, one chunk per thread
        const int i = T - 9 * c;
        float A[9];
        #pragma unroll
        for (int j = 0; j < 9; ++j) A[j] = (i == j) ? 1.0f : 0.0f;
        const int t0 = CH * c + 1;

        #pragma unroll 1
        for (int s = 0; s < CH; ++s) {
            const int t = t0 + s;
            const int o = eoff(t);
            float4 e0 = *(const float4*)(eem + o);
            float4 e1 = *(const float4*)(eem + o + 4);
            const float e8 = eem[o + 8];
            const float e[9] = { e0.x, e0.y, e0.z, e0.w,
                                 e1.x, e1.y, e1.z, e1.w, e8 };

            float an[9];
            #pragma unroll
            for (int j = 0; j < 9; ++j) an[j] = 0.0f;
            #pragma unroll
            for (int k = 0; k < 9; ++k) {
                float4 p0 = *(const float4*)(Pl + k * 12);
                float4 p1 = *(const float4*)(Pl + k * 12 + 4);
                const float p8 = Pl[k * 12 + 8];
                const float pr[9] = { p0.x, p0.y, p0.z, p0.w,
                                      p1.x, p1.y, p1.z, p1.w, p8 };
                const float ak = A[k];
                #pragma unroll
                for (int j = 0; j < 9; ++j)
                    an[j] = fmaf(ak, pr[j], an[j]);
            }
            const bool live = (t < len);
            #pragma unroll
            for (int j = 0; j < 9; ++j)
                A[j] = live ? an[j] * e[j] : A[j];
            if (s == 7) {                    // exact 2^-40; constant added at end
                #pragma unroll
                for (int j = 0; j < 9; ++j) A[j] *= 0x1p-40f;
            }
        }
        #pragma unroll
        for (int j = 0; j < 9; ++j) Cs[c * CPAD + i * 9 + j] = A[j];
    } else if (T >= 320) {
        // ---- numerator ----
        const int lane = T - 320;
        const int* lab = labels + (size_t)b * S_;
        float part = 0.0f;
        for (int t = 1 + lane; t < len; t += 64) {
            const int tp = lab[t - 1], tc = lab[t];
            part += trans[tp * 9 + tc] + em[(size_t)((b << 9) + t) * EMP + tc];
        }
        #pragma unroll
        for (int off = 32; off >= 1; off >>= 1) part += __shfl_xor(part, off, 64);
        if (lane == 0) {
            const int l0 = lab[0], le = lab[len - 1];
            const float num = start_t[l0] + em[(size_t)(b << 9) * EMP + l0]
                            + part + end_t[le];
            atomicAdd(out, -num);
        }
    }
    __syncthreads();

    // ---- phase 2a: binary tree product of 32 chunk matrices (5 levels) ----
    float* src = Cs;  float* dst = Cs2;
    float* ls  = lgA; float* ld  = lgB;
    int nn = 16;                             // output nodes this level
    #pragma unroll 1
    for (int lvl = 0; lvl < 5; ++lvl) {
        const int n = T / 9, i = T - 9 * n;
        float row[9];
        if (T < nn * 9) {
            const float* Am = src + (2 * n) * CPAD;
            const float* Bm = src + (2 * n + 1) * CPAD;
            float a[9];
            #pragma unroll
            for (int k = 0; k < 9; ++k) a[k] = Am[i * 9 + k];
            #pragma unroll
            for (int j = 0; j < 9; ++j) row[j] = 0.0f;
            #pragma unroll
            for (int k = 0; k < 9; ++k) {
                const float ak = a[k];
                #pragma unroll
                for (int j = 0; j < 9; ++j)
                    row[j] = fmaf(ak, Bm[k * 9 + j], row[j]);
            }
            float rmx = row[0];
            #pragma unroll
            for (int j = 1; j < 9; ++j) rmx = fmaxf(rmx, row[j]);
            rmx_s[n * 12 + i] = rmx;
        }
        __syncthreads();
        if (T < nn * 9) {
            float mx = rmx_s[n * 12];
            #pragma unroll
            for (int k = 1; k < 9; ++k) mx = fmaxf(mx, rmx_s[n * 12 + k]);
            const float inv = 1.0f / mx;
            #pragma unroll
            for (int j = 0; j < 9; ++j) dst[n * CPAD + i * 9 + j] = row[j] * inv;
            if (i == 0) ld[n] = ls[2 * n] + ls[2 * n + 1] + __logf(mx);
        }
        __syncthreads();
        float* t1 = src; src = dst; dst = t1;
        float* t2 = ls;  ls = ld;  ld = t2;
        nn >>= 1;
    }
    // src = final normalized matrix (node 0), ls[0] = accumulated log

    // ---- phase 2b: apply alpha0 and end transitions ----
    if (T == 0) {
        const float4* e0 = (const float4*)(em + (size_t)(b << 9) * EMP);
        float4 v0 = e0[0], v1 = e0[1], v2 = e0[2];
        float al[9] = { v0.x + start_t[0], v0.y + start_t[1], v0.z + start_t[2],
                        v0.w + start_t[3], v1.x + start_t[4], v1.y + start_t[5],
                        v1.z + start_t[6], v1.w + start_t[7], v2.x + start_t[8] };
        float m0 = al[0];
        #pragma unroll
        for (int j = 1; j < 9; ++j) m0 = fmaxf(m0, al[j]);
        float alpha[9];
        #pragma unroll
        for (int j = 0; j < 9; ++j) alpha[j] = __expf(al[j] - m0);

        float ev = 0.0f;
        #pragma unroll
        for (int j = 0; j < 9; ++j) {
            float s = 0.0f;
            #pragma unroll
            for (int i = 0; i < 9; ++i)
                s = fmaf(alpha[i], src[i * 9 + j], s);
            ev = fmaf(s, __expf(end_t[j]), ev);
        }
        // 32 chunks x 2^-40 scaling -> +1280*ln2 exact constant
        const float den = m0 + ls[0] + __logf(ev)
                        + 1280.0f * 0.6931471805599453f;
        atomicAdd(out, den);
    }
}

// ---------------------------------------------------------------------------
extern "C" void kernel_launch(void* const* d_in, const int* in_sizes, int n_in,
                              void* d_out, int out_size, void* d_ws, size_t ws_size,
                              hipStream_t stream)
{
    (void)in_sizes; (void)n_in; (void)out_size; (void)ws_size;
    const float* hidden  = (const float*)d_in[0];
    const float* W       = (const float*)d_in[1];
    const float* bias    = (const float*)d_in[2];
    const float* start_t = (const float*)d_in[3];
    const float* trans   = (const float*)d_in[4];
    const float* end_t   = (const float*)d_in[5];
    const int*   labels  = (const int*)d_in[6];
    const int*   lengths = (const int*)d_in[7];

    float* em  = (float*)d_ws;               // 64*512*16 floats = 2 MB
    float* out = (float*)d_out;

    emis_kernel<<<256, 512, 0, stream>>>(hidden, W, bias, lengths, em, out);
    crf_kernel<<<B_, 384, 0, stream>>>(em, labels, lengths,
                                       start_t, trans, end_t, out);
}